// Round 15
// baseline (51.147 us; speedup 1.0000x reference)
//
#include <hip/hip_runtime.h>
#include <hip/hip_bf16.h>

// DEC ClusteringLayer: q[i][j] = (1/(1+||x_i-c_j||^2)) / rowsum, ALPHA=1.
// Round 15: MAX-TLP + FULL-COVER.
//  - BM=64, NT=256 (4 waves), 4 independent blocks/CU (LDS ~34 KB).
//  - A: raw fp32 global_load_lds, QUAD-buffered, prefetched 3 tiles ahead
//    (2-iter drain cover); cvt fp32->bf16 at LDS-read time. Zero staging regs.
//  - B: fragment-order images read straight L2 -> REGISTERS (wave-private, no
//    LDS, no barrier coupling), two named sets Ba/Bb, 1-iter cover.
//  - Barriers: lgkmcnt(0)+s_barrier only. A-DMA drain is implicit: each wave's
//    MSTEP(J) B-register wait (vmcnt, oldest-inclusive) drains its own A(J+1)
//    DMAs (issued 2 iters earlier, before B(J)); the barrier then collects all
//    waves. Prologue orders A(0),A(1) BEFORE B(0) so the first drains cover.

typedef __attribute__((ext_vector_type(8))) short short8v;
typedef __attribute__((ext_vector_type(4))) float f32x4;

#define DDIM 512
#define KCL  256
#define BM   64
#define NT   256
#define NTILES 16
#define BTILE  8192      // shorts per fragment-order B image (256 x 32)

__device__ __forceinline__ short f2bf(float f) {
    __hip_bfloat16 h = __float2bfloat16(f);
    return __builtin_bit_cast(short, h);
}

__device__ __forceinline__ void glds16(const void* g, void* l) {
    __builtin_amdgcn_global_load_lds(
        (const __attribute__((address_space(1))) unsigned int*)g,
        (__attribute__((address_space(3))) unsigned int*)l, 16, 0, 0);
}

// ---- pre-kernel: blocks 0..63 pack clusters -> bf16 fragment-order images;
//      blocks 64..79 compute ||c||^2 ----
__global__ void prep(const float* __restrict__ cl, short* __restrict__ wsB,
                     float* __restrict__ wsC2) {
    const int t = threadIdx.x;
    if (blockIdx.x < 64) {
        const int u = blockIdx.x * 256 + t;
        const int img = u >> 10, gi = u & 1023;
        const int g = gi >> 6, lq = (gi >> 4) & 3, l15 = gi & 15;
        const float* src = cl + (size_t)(g * 16 + l15) * DDIM + img * 32 + lq * 8;
        float4 a = *(const float4*)src;
        float4 b = *(const float4*)(src + 4);
        short8v s;
        s[0]=f2bf(a.x); s[1]=f2bf(a.y); s[2]=f2bf(a.z); s[3]=f2bf(a.w);
        s[4]=f2bf(b.x); s[5]=f2bf(b.y); s[6]=f2bf(b.z); s[7]=f2bf(b.w);
        *(short8v*)&wsB[(size_t)u * 8] = s;
    } else {
        const int cidx = (blockIdx.x - 64) * 16 + (t >> 4);
        const int j = t & 15;
        const float* src = cl + (size_t)cidx * DDIM + j * 32;
        float s = 0.f;
#pragma unroll
        for (int i = 0; i < 8; ++i) {
            float4 v = ((const float4*)src)[i];
            s += v.x*v.x + v.y*v.y + v.z*v.z + v.w*v.w;
        }
        s += __shfl_xor(s, 1); s += __shfl_xor(s, 2);
        s += __shfl_xor(s, 4); s += __shfl_xor(s, 8);
        if (j == 0) wsC2[cidx] = s;
    }
}

#define SFENCE()  __builtin_amdgcn_sched_barrier(0)
#define BARLGKM() asm volatile("s_waitcnt lgkmcnt(0)\ns_barrier" ::: "memory")
#define BARP()    asm volatile("s_waitcnt vmcnt(8) lgkmcnt(0)\ns_barrier" ::: "memory")

__global__ __launch_bounds__(NT, 4)
void dec_main(const float* __restrict__ x, const short* __restrict__ wsB,
              const float* __restrict__ wsC2, float* __restrict__ out) {
    __shared__ __align__(16) float lAf[4][2048];   // 32 KB: A tiles fp32, quad-buf
    __shared__ float s_x2[BM];
    __shared__ float s_rs[4][BM];

    const int t = threadIdx.x, lane = t & 63, cg = t >> 6;   // 4 waves = 4 col-groups
    const int l15 = lane & 15, lq = lane >> 4;
    const int row0 = blockIdx.x * BM;

    // ---- A-DMA mapping: thread t, 2 glds of 16B per tile ----
    // float slot = mb*512 + half*256 + lane_s*4 + j ; row = mb*16 + (lane_s&15),
    // col = (lane_s>>4)*8 + half*4 + j. call0: slot=4t (mb=t>>7); call1: +1024 (mb+2).
    const int rA = ((t >> 7) << 4) + (t & 15);
    const int cA = (((t >> 4) & 3) << 3) + (((t >> 6) & 1) << 2);
    const float* ga0 = x + (size_t)(row0 + rA) * DDIM + cA;        // rows 0..31
    const float* ga1 = ga0 + (size_t)32 * DDIM;                    // rows 32..63

    // B fragment base (wave-private, coalesced lane*16B)
    const short* bb = wsB + (size_t)cg * 2048 + (size_t)lane * 8;

    f32x4 acc[4][4];
#pragma unroll
    for (int m = 0; m < 4; ++m)
#pragma unroll
        for (int n = 0; n < 4; ++n) acc[m][n] = (f32x4){0.f,0.f,0.f,0.f};
    float x2p[4] = {0.f, 0.f, 0.f, 0.f};
    short8v Ba[4], Bb[4];

#define GLDSA(TT, P)                                                 \
    {  glds16(ga0 + (TT) * 32, &lAf[P][t * 4]);                      \
       glds16(ga1 + (TT) * 32, &lAf[P][t * 4 + 1024]); }

#define LOADB(TT, S)                                                 \
    {  const short* bt = bb + (size_t)(TT) * BTILE;                  \
       S[0] = *(const short8v*)(bt);                                 \
       S[1] = *(const short8v*)(bt + 512);                           \
       S[2] = *(const short8v*)(bt + 1024);                          \
       S[3] = *(const short8v*)(bt + 1536); }

#define MSTEP(P, S)                                                              \
    {  _Pragma("unroll")                                                         \
       for (int m = 0; m < 4; ++m) {                                             \
           float4 alo = *(const float4*)&lAf[P][m*512 + lane*4];                 \
           float4 ahi = *(const float4*)&lAf[P][m*512 + 256 + lane*4];           \
           short8v af;                                                           \
           af[0]=f2bf(alo.x); af[1]=f2bf(alo.y); af[2]=f2bf(alo.z); af[3]=f2bf(alo.w); \
           af[4]=f2bf(ahi.x); af[5]=f2bf(ahi.y); af[6]=f2bf(ahi.z); af[7]=f2bf(ahi.w); \
           if (cg == 0)                                                          \
               x2p[m] += alo.x*alo.x + alo.y*alo.y + alo.z*alo.z + alo.w*alo.w   \
                       + ahi.x*ahi.x + ahi.y*ahi.y + ahi.z*ahi.z + ahi.w*ahi.w;  \
           acc[m][0] = __builtin_amdgcn_mfma_f32_16x16x32_bf16(af, S[0], acc[m][0], 0,0,0); \
           acc[m][1] = __builtin_amdgcn_mfma_f32_16x16x32_bf16(af, S[1], acc[m][1], 0,0,0); \
           acc[m][2] = __builtin_amdgcn_mfma_f32_16x16x32_bf16(af, S[2], acc[m][2], 0,0,0); \
           acc[m][3] = __builtin_amdgcn_mfma_f32_16x16x32_bf16(af, S[3], acc[m][3], 0,0,0); \
       } }

    // ITER(J): issue B(J+1) then A(J+3); MSTEP(J) [implicit vmcnt wait on B(J)
    // drains this wave's A(J+1), issued 2 iters earlier]; barrier collects.
#define ITER(J, BCUR, BNXT)                                                      \
    {  if ((J) + 1 < NTILES) { LOADB((J)+1, BNXT); }                             \
       SFENCE();                                                                 \
       if ((J) + 3 < NTILES) { GLDSA((J)+3, ((J)+3)&3); }                        \
       SFENCE();                                                                 \
       MSTEP((J)&3, BCUR);                                                       \
       SFENCE();                                                                 \
       if ((J) + 1 < NTILES) { BARLGKM(); }                                      \
       SFENCE(); }

    // ---- prologue: A(0),A(1) BEFORE B(0) (so B(0)'s wait drains them);
    //      then A(2). Barrier drains A(0) only (vmcnt 8 leaves A1,B0,A2). ----
    GLDSA(0, 0);
    GLDSA(1, 1);
    SFENCE();
    LOADB(0, Ba);
    SFENCE();
    GLDSA(2, 2);
    SFENCE();
    BARP();
    SFENCE();

    ITER( 0, Ba, Bb)
    ITER( 1, Bb, Ba)
    ITER( 2, Ba, Bb)
    ITER( 3, Bb, Ba)
    ITER( 4, Ba, Bb)
    ITER( 5, Bb, Ba)
    ITER( 6, Ba, Bb)
    ITER( 7, Bb, Ba)
    ITER( 8, Ba, Bb)
    ITER( 9, Bb, Ba)
    ITER(10, Ba, Bb)
    ITER(11, Bb, Ba)
    ITER(12, Ba, Bb)
    ITER(13, Bb, Ba)
    ITER(14, Ba, Bb)
    ITER(15, Bb, Ba)          // MSTEP only

    // ---- ||x||^2: computed by wave 0 during MSTEP; reduce over lq lanes ----
#pragma unroll
    for (int m = 0; m < 4; ++m) {
        float v = x2p[m];
        v += __shfl_xor(v, 16); v += __shfl_xor(v, 32);
        if (cg == 0 && lq == 0) s_x2[m*16 + l15] = v;
    }
    __syncthreads();

    // ---- epilogue: d2 -> q_unnorm (C/D: col=l15, row=lq*4+r) ----
    float c2a[4];
#pragma unroll
    for (int n = 0; n < 4; ++n) c2a[n] = wsC2[cg*64 + n*16 + l15];

#pragma unroll
    for (int m = 0; m < 4; ++m)
#pragma unroll
        for (int n = 0; n < 4; ++n)
#pragma unroll
            for (int r = 0; r < 4; ++r) {
                const int rw = m*16 + lq*4 + r;
                float d2 = fmaxf(s_x2[rw] + c2a[n] - 2.0f * acc[m][n][r], 0.0f);
                acc[m][n][r] = 1.0f / (1.0f + d2);
            }

    // ---- row sums: 16-lane shuffle, per-cg slot (deterministic) ----
#pragma unroll
    for (int m = 0; m < 4; ++m)
#pragma unroll
        for (int r = 0; r < 4; ++r) {
            float p = acc[m][0][r] + acc[m][1][r] + acc[m][2][r] + acc[m][3][r];
            p += __shfl_xor(p, 1); p += __shfl_xor(p, 2);
            p += __shfl_xor(p, 4); p += __shfl_xor(p, 8);
            if (l15 == 0) s_rs[cg][m*16 + lq*4 + r] = p;
        }
    __syncthreads();

    // ---- normalize + store ----
#pragma unroll
    for (int m = 0; m < 4; ++m)
#pragma unroll
        for (int r = 0; r < 4; ++r) {
            const int rw = m*16 + lq*4 + r;
            const float rinv = 1.0f / (s_rs[0][rw] + s_rs[1][rw] + s_rs[2][rw] + s_rs[3][rw]);
            float* o = out + (size_t)(row0 + rw) * KCL + cg*64 + l15;
#pragma unroll
            for (int n = 0; n < 4; ++n)
                o[n * 16] = acc[m][n][r] * rinv;
        }
}

extern "C" void kernel_launch(void* const* d_in, const int* in_sizes, int n_in,
                              void* d_out, int out_size, void* d_ws, size_t ws_size,
                              hipStream_t stream) {
    const float* x  = (const float*)d_in[0];
    const float* cl = (const float*)d_in[1];
    float* out = (float*)d_out;
    short* wsB  = (short*)d_ws;
    float* wsC2 = (float*)((char*)d_ws + (size_t)NTILES * BTILE * sizeof(short)); // +256 KB

    prep<<<80, 256, 0, stream>>>(cl, wsB, wsC2);
    const int B = in_sizes[0] / DDIM;     // 65536
    dec_main<<<B / BM, NT, 0, stream>>>(x, wsB, wsC2, out);
}